// Round 8
// baseline (259.475 us; speedup 1.0000x reference)
//
#include <hip/hip_runtime.h>
#include <stdint.h>
#include <math.h>

typedef __attribute__((ext_vector_type(8))) short short8;
typedef __attribute__((ext_vector_type(4))) float floatx4;

// ---------------- LDS layout (26624 B + flag -> 4 blocks/CU at 8 waves) ----------------
#define L_HF    0        // 16384: W1 B-frags, then h B-frags: [ct(4)][ks(4)][lane(64)] x 16B
#define L_SRC   16384    // 2048 : att_src [4][128] f32 (pre-scaled by log2e)
#define L_DST   18432    // 2048 : att_dst [4][128] f32 (pre-scaled by log2e)
#define L_MASK  20480    // 2048 : mask bits [128 rows][16 B]
#define L_H2P   22528    // 4096 : layer-2 partials float2[4 heads][128 nodes]; tail reuses
#define L_SIZE  26624

#define WS_H2_FLOATS  (1024*256)          // 1 MB of h2 partials
#define WS_CNT_OFF    (WS_H2_FLOATS*4)    // 128 u32 tickets after that

union F8 { short8 s8; uint32_t u[4]; };

#if __has_builtin(__builtin_amdgcn_exp2f)
#define EXP2F __builtin_amdgcn_exp2f
#else
#define EXP2F exp2f
#endif
#define LOG2E 1.4426950408889634f

__device__ __forceinline__ uint32_t packbf(float a, float b){
  uint32_t ua = __float_as_uint(a), ub = __float_as_uint(b);
  uint32_t ra = (ua + 0x7fffu + ((ua>>16)&1u)) >> 16;   // RNE bf16
  uint32_t rb = (ub + 0x7fffu + ((ub>>16)&1u)) >> 16;
  return ra | (rb<<16);
}
// truncation pack (1 inst): low16 = hi16(a), high16 = hi16(b)
__device__ __forceinline__ uint32_t packbf_t(float a, float b){
  return __builtin_amdgcn_perm(__float_as_uint(b), __float_as_uint(a), 0x07060302u);
}
__device__ __forceinline__ float fast_tanh(float x){
  float e = __expf(2.f*x);
  return 1.f - 2.f*__builtin_amdgcn_rcpf(e + 1.f);
}
// sum over the 16-lane DPP row via row_ror — result valid in ALL lanes. Pure VALU.
__device__ __forceinline__ float red16(float x){
  x += __int_as_float(__builtin_amdgcn_update_dpp(0, __float_as_int(x), 0x128, 0xf, 0xf, true)); // row_ror:8
  x += __int_as_float(__builtin_amdgcn_update_dpp(0, __float_as_int(x), 0x124, 0xf, 0xf, true)); // row_ror:4
  x += __int_as_float(__builtin_amdgcn_update_dpp(0, __float_as_int(x), 0x122, 0xf, 0xf, true)); // row_ror:2
  x += __int_as_float(__builtin_amdgcn_update_dpp(0, __float_as_int(x), 0x121, 0xf, 0xf, true)); // row_ror:1
  return x;
}

// ---- fused GAT: one block per (s, b, head-half), 8 waves; last-of-8 runs the tail ----
__global__ __launch_bounds__(512,8) void gat_fused(
    const float* __restrict__ x,  const float* __restrict__ emb,
    const int* __restrict__ adj,  const float* __restrict__ w1,
    const float* __restrict__ a_src1, const float* __restrict__ a_dst1,
    const float* __restrict__ b1, const float* __restrict__ w2,
    const float* __restrict__ a_src2, const float* __restrict__ a_dst2,
    const float* __restrict__ b2,
    float* __restrict__ ws_h2, uint32_t* __restrict__ cnt,
    float* __restrict__ outp)
{
  __shared__ __align__(16) char smem[L_SIZE];
  __shared__ uint32_t s_last;
  char*     hf    = smem + L_HF;
  uint32_t* hf_u  = (uint32_t*)(smem + L_HF);
  float*    src_l = (float*)(smem + L_SRC);
  float*    dst_l = (float*)(smem + L_DST);
  uint32_t* mask_l= (uint32_t*)(smem + L_MASK);
  const uint4* mask4 = (const uint4*)(smem + L_MASK);
  float2*   h2p   = (float2*)(smem + L_H2P);

  const int t    = threadIdx.x;
  const int blk  = blockIdx.x;
  const int s    = blk >> 8;
  const int bb   = (blk & 255) >> 1;
  const int half = blk & 1;
  const int lane = t & 63, w = t >> 6;
  const int of = lane & 15, kg = lane >> 4;

  // ---------- Phase 0a: A-frags direct from global (rows w*16+of) ----------
  const int arow = w*16 + of;
  const float* xrow = x   + ((size_t)bb*128 + arow)*64;
  const float* erow = emb + ((size_t)bb*128 + arow)*64;
  short8 af[4];
  #pragma unroll
  for (int ks=0; ks<4; ++ks){
    int k = ks*32 + kg*8;
    const float* p = (k<64) ? (xrow+k) : (erow + (k-64));
    float4 f0 = *(const float4*)p, f1 = *(const float4*)(p+4);
    F8 fr;
    fr.u[0]=packbf(f0.x,f0.y); fr.u[1]=packbf(f0.z,f0.w);
    fr.u[2]=packbf(f1.x,f1.y); fr.u[3]=packbf(f1.z,f1.w);
    af[ks]=fr.s8;
  }

  // ---------- Phase 0b: stage this block's 4 heads of W1 as bf16 B-frags ----------
  {
    const float* w1s = w1 + (size_t)s*16384 + half*8192;  // 4 heads x 128 x 16
    #pragma unroll
    for (int r=0; r<2; ++r){
      int q = t + r*512;                     // 0..1023 = (ct*4+ks)*64 + qlane
      int ql = q & 63, ks = (q>>6)&3, ct = q>>8;
      const float* wp = w1s + ct*2048 + (ks*32 + (ql>>4)*8)*16 + (ql&15);
      F8 fr;
      fr.u[0]=packbf(wp[0],  wp[16]);
      fr.u[1]=packbf(wp[32], wp[48]);
      fr.u[2]=packbf(wp[64], wp[80]);
      fr.u[3]=packbf(wp[96], wp[112]);
      *(short8*)(hf + ((ct*4+ks)*64 + ql)*16) = fr.s8;
    }
  }

  // ---------- Phase 0c: adjacency ballot -> mask bits (wave w: rows w*16..+15) ----------
  {
    const int* adjb = adj + (size_t)bb*16384;
    #pragma unroll 4
    for (int rr=0; rr<16; ++rr){
      const int row = w*16 + rr;
      const int* ar = adjb + row*128;
      uint64_t m0 = __ballot(ar[lane] != 0);
      uint64_t m1 = __ballot(ar[64+lane] != 0);
      if (lane == 0)
        ((uint4*)mask_l)[row] = make_uint4((uint32_t)m0,(uint32_t)(m0>>32),
                                           (uint32_t)m1,(uint32_t)(m1>>32));
    }
  }
  __syncthreads();

  // ---------- Phase 1: h = x0 @ W1 via MFMA ----------
  floatx4 acc[4];
  #pragma unroll
  for (int ct=0; ct<4; ++ct) acc[ct]=(floatx4){0.f,0.f,0.f,0.f};
  #pragma unroll
  for (int ct=0; ct<4; ++ct)
    #pragma unroll
    for (int ks=0; ks<4; ++ks){
      short8 bfr = *(const short8*)(hf + ((ct*4+ks)*64 + lane)*16);
      acc[ct] = __builtin_amdgcn_mfma_f32_16x16x32_bf16(af[ks], bfr, acc[ct], 0,0,0);
    }
  __syncthreads();                            // all W1-frag reads done before h overwrite

  // epilogue: tanh -> att partials (x log2e) via DPP row-reduce; h -> LDS in B-frag order
  const int ks_h = w>>1, kgp = (w&1)*2 + (kg>>1), vv = (kg&1)*2;
  #pragma unroll
  for (int ct=0; ct<4; ++ct){
    const int ghd = half*4 + ct;
    float asv = a_src1[s*128 + ghd*16 + of] * LOG2E;
    float adv = a_dst1[s*128 + ghd*16 + of] * LOG2E;
    float ps[4], pd[4];
    #pragma unroll
    for (int r=0; r<4; ++r){
      float th = fast_tanh(acc[ct][r]);
      ps[r] = red16(th*asv); pd[r] = red16(th*adv);
    }
    if (of==0){
      #pragma unroll
      for (int r=0; r<4; ++r){
        int i = w*16 + kg*4 + r;
        src_l[ct*128+i]=ps[r]; dst_l[ct*128+i]=pd[r];
      }
    }
    uint32_t p0 = packbf(acc[ct][0], acc[ct][1]);
    uint32_t p1 = packbf(acc[ct][2], acc[ct][3]);
    uint32_t* dsth = hf_u + ((ct*4+ks_h)*64 + kgp*16 + of)*4 + vv;
    *(uint2*)dsth = make_uint2(p0, p1);
  }
  __syncthreads();

  // ---------- Phase 2: softmax(lrelu(src+dst)) @ h, fused elu + W2 dot ----------
  const int lhd = w >> 1;                     // 2 waves per head
  const int ghd = half*4 + lhd;
  const int rtb = (w&1)*4;                    // this wave's row-tile base
  float b1v  = b1[of];
  float w2c0 = w2[s*256 + (ghd*16+of)*2 + 0];
  float w2c1 = w2[s*256 + (ghd*16+of)*2 + 1];
  short8 hb[4];
  #pragma unroll
  for (int ks=0; ks<4; ++ks)
    hb[ks] = *(const short8*)(hf + ((lhd*4+ks)*64 + lane)*16);

  #pragma unroll
  for (int rtl=0; rtl<4; ++rtl){
    const int rt = rtb + rtl;
    const int im = rt*16 + of;                // A-layout row
    float srcv = src_l[lhd*128 + im];
    uint4 mrow = mask4[im];
    floatx4 acc2 = (floatx4){0.f,0.f,0.f,0.f};
    float zp = 0.f;
    #pragma unroll
    for (int ks=0; ks<4; ++ks){
      const float* dp = dst_l + lhd*128 + ks*32 + kg*8;
      float4 d0 = *(const float4*)dp, d1 = *(const float4*)(dp+4);
      uint32_t mw = (ks==0)?mrow.x:(ks==1)?mrow.y:(ks==2)?mrow.z:mrow.w;
      uint32_t mbyte = mw >> (kg*8);
      float dj[8] = {d0.x,d0.y,d0.z,d0.w,d1.x,d1.y,d1.z,d1.w};
      float e[8];
      #pragma unroll
      for (int jj=0; jj<8; ++jj){
        float t0 = srcv + dj[jj];             // already x log2e
        float lr = fmaxf(t0, 0.2f*t0);
        float ev = EXP2F(lr);
        ev = ((mbyte>>jj)&1u) ? ev : 0.f;
        e[jj]=ev; zp += ev;
      }
      F8 fr;
      fr.u[0]=packbf_t(e[0],e[1]); fr.u[1]=packbf_t(e[2],e[3]);
      fr.u[2]=packbf_t(e[4],e[5]); fr.u[3]=packbf_t(e[6],e[7]);
      acc2 = __builtin_amdgcn_mfma_f32_16x16x32_bf16(fr.s8, hb[ks], acc2, 0,0,0);
    }
    float zr = zp + __shfl_xor(zp,16); zr += __shfl_xor(zr,32);
    float zi = __builtin_amdgcn_rcpf(zr);
    float pc0[4], pc1[4];
    #pragma unroll
    for (int r=0; r<4; ++r){
      float ziR = __shfl(zi, kg*4+r);
      float o  = fmaf(acc2[r], ziR, b1v);
      float oe = (o>0.f) ? o : (__expf(o)-1.f);   // elu
      pc0[r] = red16(oe*w2c0);
      pc1[r] = red16(oe*w2c1);
    }
    if (of==0){
      #pragma unroll
      for (int r=0; r<4; ++r){
        int i = rt*16 + kg*4 + r;
        h2p[lhd*128 + i] = make_float2(pc0[r], pc1[r]);
      }
    }
  }
  __syncthreads();

  // ---------- block-partial h2 (sum over this block's 4 heads) -> ws ----------
  if (t < 256){
    const int jn = t>>1, cc = t&1;
    float hv = 0.f;
    #pragma unroll
    for (int hd2=0; hd2<4; ++hd2){
      float2 p = h2p[hd2*128+jn];
      hv += cc ? p.y : p.x;
    }
    ws_h2[(size_t)blk*256 + t] = hv;
  }

  // ---------- ticket: last of this bb's 8 blocks runs the tail ----------
  __threadfence();                            // release our ws_h2 stores (device scope)
  __syncthreads();                            // all stores issued; h2p free for reuse
  if (t==0) s_last = (atomicAdd(&cnt[bb], 1u) == 7u) ? 1u : 0u;
  __syncthreads();
  if (!s_last) return;
  __threadfence();                            // acquire: other blocks' ws_h2 now visible

  // ---------- tail: layer-2 ego-row softmax + log_softmax + mean over S ----------
  {
    float* d2_l = (float*)(smem + L_H2P);           // reuse h2p region
    float* red  = (float*)(smem + L_H2P + 512);
    float* srcE = (float*)(smem + L_H2P + 576);
    const int jn = t>>1, cc = t&1;
    const bool act = (t<256);
    uint32_t bit = 0;
    if (act) bit = (mask_l[127*4 + (jn>>5)] >> (jn&31)) & 1u;
    float acc0=0.f, acc1=0.f;
    for (int ss=0; ss<4; ++ss){
      float hv=0.f, ps2=0.f, pd2=0.f;
      if (act){
        hv = ws_h2[(size_t)(ss*256 + bb*2 + 0)*256 + t]
           + ws_h2[(size_t)(ss*256 + bb*2 + 1)*256 + t];
        float th2 = fast_tanh(hv);
        ps2 = th2*a_src2[ss*2+cc];
        pd2 = th2*a_dst2[ss*2+cc];
        ps2 += __shfl_xor(ps2,1);
        pd2 += __shfl_xor(pd2,1);
      }
      if (ss) __syncthreads();               // WAR on d2_l/srcE/red
      if (act){
        if (cc==0) d2_l[jn]=pd2;
        if (t==254) *srcE=ps2;               // ego node jn=127
      }
      __syncthreads();
      float v = -1e9f;
      if (act){
        float t0 = *srcE + d2_l[jn];
        float lg = fmaxf(t0, 0.2f*t0);
        v = bit ? lg : -1e9f;
      }
      float mloc = v;
      #pragma unroll
      for (int off=32; off>=1; off>>=1) mloc = fmaxf(mloc, __shfl_xor(mloc,off));
      if (act && lane==0) red[w]=mloc;
      __syncthreads();
      float M = fmaxf(fmaxf(red[0],red[1]), fmaxf(red[2],red[3]));
      float e2 = act ? __expf(v-M) : 0.f;
      float vA = e2*hv;
      float vZ = (act && cc==0) ? e2 : 0.f;
      #pragma unroll
      for (int off=2; off<=32; off<<=1){ vA+=__shfl_xor(vA,off); vZ+=__shfl_xor(vZ,off); }
      if (act && lane==0){ red[4+w]=vA; red[12+w]=vZ; }
      if (act && lane==1){ red[8+w]=vA; }
      __syncthreads();
      if (t==0){
        float S0 = red[4]+red[5]+red[6]+red[7];
        float S1 = red[8]+red[9]+red[10]+red[11];
        float Z  = red[12]+red[13]+red[14]+red[15];
        float o0 = S0/Z + b2[0];
        float o1 = S1/Z + b2[1];
        float mm = fmaxf(o0,o1);
        float lse = mm + logf(__expf(o0-mm)+__expf(o1-mm));
        acc0 += 0.25f*(o0 - lse);
        acc1 += 0.25f*(o1 - lse);
      }
    }
    if (t==0){ outp[bb*2+0]=acc0; outp[bb*2+1]=acc1; }
  }
}

extern "C" void kernel_launch(void* const* d_in, const int* in_sizes, int n_in,
                              void* d_out, int out_size, void* d_ws, size_t ws_size,
                              hipStream_t stream) {
  const float* x      = (const float*)d_in[0];
  const float* emb    = (const float*)d_in[1];
  const int*   adj    = (const int*)d_in[2];
  const float* w1     = (const float*)d_in[3];
  const float* a_src1 = (const float*)d_in[4];
  const float* a_dst1 = (const float*)d_in[5];
  const float* b1     = (const float*)d_in[6];
  const float* w2     = (const float*)d_in[7];
  const float* a_src2 = (const float*)d_in[8];
  const float* a_dst2 = (const float*)d_in[9];
  const float* b2     = (const float*)d_in[10];

  float*    ws_h2 = (float*)d_ws;
  uint32_t* cnt   = (uint32_t*)((char*)d_ws + WS_CNT_OFF);

  hipMemsetAsync(cnt, 0, 128*sizeof(uint32_t), stream);
  gat_fused<<<dim3(1024), dim3(512), 0, stream>>>(x, emb, adj, w1, a_src1, a_dst1,
                                                  b1, w2, a_src2, a_dst2, b2,
                                                  ws_h2, cnt, (float*)d_out);
}

// Round 9
// 137.208 us; speedup vs baseline: 1.8911x; 1.8911x over previous
//
#include <hip/hip_runtime.h>
#include <stdint.h>
#include <math.h>

typedef __attribute__((ext_vector_type(8))) short short8;
typedef __attribute__((ext_vector_type(4))) float floatx4;

// ---------------- LDS layout (26624 B -> 4 blocks/CU at 8 waves) ----------------
#define L_HF    0        // 16384: W1 B-frags, then h B-frags: [ct(4)][ks(4)][lane(64)] x 16B
#define L_SRC   16384    // 2048 : att_src [4][128] f32 (pre-scaled by log2e)
#define L_DST   18432    // 2048 : att_dst [4][128] f32 (pre-scaled by log2e)
#define L_MASK  20480    // 2048 : mask bits [128 rows][16 B]
#define L_H2P   22528    // 4096 : layer-2 partials float2[4 heads][128 nodes]
#define L_SIZE  26624

union F8 { short8 s8; uint32_t u[4]; };

#if __has_builtin(__builtin_amdgcn_exp2f)
#define EXP2F __builtin_amdgcn_exp2f
#else
#define EXP2F exp2f
#endif
#define LOG2E 1.4426950408889634f

__device__ __forceinline__ uint32_t packbf(float a, float b){
  uint32_t ua = __float_as_uint(a), ub = __float_as_uint(b);
  uint32_t ra = (ua + 0x7fffu + ((ua>>16)&1u)) >> 16;   // RNE bf16
  uint32_t rb = (ub + 0x7fffu + ((ub>>16)&1u)) >> 16;
  return ra | (rb<<16);
}
// truncation pack (1 inst): low16 = hi16(a), high16 = hi16(b)
__device__ __forceinline__ uint32_t packbf_t(float a, float b){
  return __builtin_amdgcn_perm(__float_as_uint(b), __float_as_uint(a), 0x07060302u);
}
__device__ __forceinline__ float fast_tanh(float x){
  float e = __expf(2.f*x);
  return 1.f - 2.f*__builtin_amdgcn_rcpf(e + 1.f);
}
// sum over the 16-lane DPP row via row_ror — result valid in ALL lanes. Pure VALU.
__device__ __forceinline__ float red16(float x){
  x += __int_as_float(__builtin_amdgcn_update_dpp(0, __float_as_int(x), 0x128, 0xf, 0xf, true)); // row_ror:8
  x += __int_as_float(__builtin_amdgcn_update_dpp(0, __float_as_int(x), 0x124, 0xf, 0xf, true)); // row_ror:4
  x += __int_as_float(__builtin_amdgcn_update_dpp(0, __float_as_int(x), 0x122, 0xf, 0xf, true)); // row_ror:2
  x += __int_as_float(__builtin_amdgcn_update_dpp(0, __float_as_int(x), 0x121, 0xf, 0xf, true)); // row_ror:1
  return x;
}

// ---- fused GAT: one block per (s, b, head-half), 8 waves ----
__global__ __launch_bounds__(512,8) void gat_fused(
    const float* __restrict__ x,  const float* __restrict__ emb,
    const int* __restrict__ adj,  const float* __restrict__ w1,
    const float* __restrict__ a_src1, const float* __restrict__ a_dst1,
    const float* __restrict__ b1, const float* __restrict__ w2,
    float* __restrict__ ws_h2)
{
  __shared__ __align__(16) char smem[L_SIZE];
  char*     hf    = smem + L_HF;
  uint32_t* hf_u  = (uint32_t*)(smem + L_HF);
  float*    src_l = (float*)(smem + L_SRC);
  float*    dst_l = (float*)(smem + L_DST);
  uint32_t* mask_l= (uint32_t*)(smem + L_MASK);
  const uint4* mask4 = (const uint4*)(smem + L_MASK);
  float2*   h2p   = (float2*)(smem + L_H2P);

  const int t    = threadIdx.x;
  const int blk  = blockIdx.x;
  const int s    = blk >> 8;
  const int bb   = (blk & 255) >> 1;
  const int half = blk & 1;
  const int lane = t & 63, w = t >> 6;
  const int of = lane & 15, kg = lane >> 4;

  // ---------- Phase 0a: A-frags direct from global (rows w*16+of) ----------
  const int arow = w*16 + of;
  const float* xrow = x   + ((size_t)bb*128 + arow)*64;
  const float* erow = emb + ((size_t)bb*128 + arow)*64;
  short8 af[4];
  #pragma unroll
  for (int ks=0; ks<4; ++ks){
    int k = ks*32 + kg*8;
    const float* p = (k<64) ? (xrow+k) : (erow + (k-64));
    float4 f0 = *(const float4*)p, f1 = *(const float4*)(p+4);
    F8 fr;
    fr.u[0]=packbf(f0.x,f0.y); fr.u[1]=packbf(f0.z,f0.w);
    fr.u[2]=packbf(f1.x,f1.y); fr.u[3]=packbf(f1.z,f1.w);
    af[ks]=fr.s8;
  }

  // ---------- Phase 0b: stage this block's 4 heads of W1 as bf16 B-frags ----------
  {
    const float* w1s = w1 + (size_t)s*16384 + half*8192;  // 4 heads x 128 x 16
    #pragma unroll
    for (int r=0; r<2; ++r){
      int q = t + r*512;                     // 0..1023 = (ct*4+ks)*64 + qlane
      int ql = q & 63, ks = (q>>6)&3, ct = q>>8;
      const float* wp = w1s + ct*2048 + (ks*32 + (ql>>4)*8)*16 + (ql&15);
      F8 fr;
      fr.u[0]=packbf(wp[0],  wp[16]);
      fr.u[1]=packbf(wp[32], wp[48]);
      fr.u[2]=packbf(wp[64], wp[80]);
      fr.u[3]=packbf(wp[96], wp[112]);
      *(short8*)(hf + ((ct*4+ks)*64 + ql)*16) = fr.s8;
    }
  }

  // ---------- Phase 0c: adjacency ballot -> mask bits (wave w: rows w*16..+15) ----------
  {
    const int* adjb = adj + (size_t)bb*16384;
    #pragma unroll 4
    for (int rr=0; rr<16; ++rr){
      const int row = w*16 + rr;
      const int* ar = adjb + row*128;
      uint64_t m0 = __ballot(ar[lane] != 0);
      uint64_t m1 = __ballot(ar[64+lane] != 0);
      if (lane == 0)
        ((uint4*)mask_l)[row] = make_uint4((uint32_t)m0,(uint32_t)(m0>>32),
                                           (uint32_t)m1,(uint32_t)(m1>>32));
    }
  }
  __syncthreads();

  // ---------- Phase 1: h = x0 @ W1 via MFMA ----------
  floatx4 acc[4];
  #pragma unroll
  for (int ct=0; ct<4; ++ct) acc[ct]=(floatx4){0.f,0.f,0.f,0.f};
  #pragma unroll
  for (int ct=0; ct<4; ++ct)
    #pragma unroll
    for (int ks=0; ks<4; ++ks){
      short8 bfr = *(const short8*)(hf + ((ct*4+ks)*64 + lane)*16);
      acc[ct] = __builtin_amdgcn_mfma_f32_16x16x32_bf16(af[ks], bfr, acc[ct], 0,0,0);
    }
  __syncthreads();                            // all W1-frag reads done before h overwrite

  // epilogue: tanh -> att partials (x log2e) via DPP row-reduce; h -> LDS in B-frag order
  const int ks_h = w>>1, kgp = (w&1)*2 + (kg>>1), vv = (kg&1)*2;
  #pragma unroll
  for (int ct=0; ct<4; ++ct){
    const int ghd = half*4 + ct;
    float asv = a_src1[s*128 + ghd*16 + of] * LOG2E;
    float adv = a_dst1[s*128 + ghd*16 + of] * LOG2E;
    float ps[4], pd[4];
    #pragma unroll
    for (int r=0; r<4; ++r){
      float th = fast_tanh(acc[ct][r]);
      ps[r] = red16(th*asv); pd[r] = red16(th*adv);
    }
    if (of==0){
      #pragma unroll
      for (int r=0; r<4; ++r){
        int i = w*16 + kg*4 + r;
        src_l[ct*128+i]=ps[r]; dst_l[ct*128+i]=pd[r];
      }
    }
    uint32_t p0 = packbf(acc[ct][0], acc[ct][1]);
    uint32_t p1 = packbf(acc[ct][2], acc[ct][3]);
    uint32_t* dsth = hf_u + ((ct*4+ks_h)*64 + kgp*16 + of)*4 + vv;
    *(uint2*)dsth = make_uint2(p0, p1);
  }
  __syncthreads();

  // ---------- Phase 2: softmax(lrelu(src+dst)) @ h, fused elu + W2 dot ----------
  // row-tiles paired 2-at-a-time: dst loaded once per ks per pair, 2 independent
  // exp->pack->MFMA chains for ILP. hbk loaded per-ks (keeps live regs < 64).
  const int lhd = w >> 1;                     // 2 waves per head
  const int ghd = half*4 + lhd;
  const int rtb = (w&1)*4;                    // this wave's row-tile base
  float b1v  = b1[of];
  float w2c0 = w2[s*256 + (ghd*16+of)*2 + 0];
  float w2c1 = w2[s*256 + (ghd*16+of)*2 + 1];

  #pragma unroll
  for (int pp=0; pp<2; ++pp){
    const int rt0 = rtb + pp*2, rt1 = rt0 + 1;
    const int im0 = rt0*16 + of, im1 = rt1*16 + of;
    float srcv0 = src_l[lhd*128 + im0];
    float srcv1 = src_l[lhd*128 + im1];
    uint4 mrow0 = mask4[im0];
    uint4 mrow1 = mask4[im1];
    floatx4 acc20 = (floatx4){0.f,0.f,0.f,0.f};
    floatx4 acc21 = (floatx4){0.f,0.f,0.f,0.f};
    float zp0 = 0.f, zp1 = 0.f;
    #pragma unroll
    for (int ks=0; ks<4; ++ks){
      const float* dp = dst_l + lhd*128 + ks*32 + kg*8;
      float4 d0 = *(const float4*)dp, d1 = *(const float4*)(dp+4);
      short8 hbk = *(const short8*)(hf + ((lhd*4+ks)*64 + lane)*16);
      uint32_t mw0 = (ks==0)?mrow0.x:(ks==1)?mrow0.y:(ks==2)?mrow0.z:mrow0.w;
      uint32_t mw1 = (ks==0)?mrow1.x:(ks==1)?mrow1.y:(ks==2)?mrow1.z:mrow1.w;
      uint32_t mb0 = mw0 >> (kg*8);
      uint32_t mb1 = mw1 >> (kg*8);
      float dj[8] = {d0.x,d0.y,d0.z,d0.w,d1.x,d1.y,d1.z,d1.w};
      float e0[8], e1[8];
      #pragma unroll
      for (int jj=0; jj<8; ++jj){
        float t0 = srcv0 + dj[jj];
        float t1 = srcv1 + dj[jj];
        float l0 = fmaxf(t0, 0.2f*t0);
        float l1 = fmaxf(t1, 0.2f*t1);
        float v0 = EXP2F(l0);
        float v1 = EXP2F(l1);
        v0 = ((mb0>>jj)&1u) ? v0 : 0.f;
        v1 = ((mb1>>jj)&1u) ? v1 : 0.f;
        e0[jj]=v0; zp0 += v0;
        e1[jj]=v1; zp1 += v1;
      }
      F8 fr0, fr1;
      fr0.u[0]=packbf_t(e0[0],e0[1]); fr0.u[1]=packbf_t(e0[2],e0[3]);
      fr0.u[2]=packbf_t(e0[4],e0[5]); fr0.u[3]=packbf_t(e0[6],e0[7]);
      fr1.u[0]=packbf_t(e1[0],e1[1]); fr1.u[1]=packbf_t(e1[2],e1[3]);
      fr1.u[2]=packbf_t(e1[4],e1[5]); fr1.u[3]=packbf_t(e1[6],e1[7]);
      acc20 = __builtin_amdgcn_mfma_f32_16x16x32_bf16(fr0.s8, hbk, acc20, 0,0,0);
      acc21 = __builtin_amdgcn_mfma_f32_16x16x32_bf16(fr1.s8, hbk, acc21, 0,0,0);
    }
    #pragma unroll
    for (int pr=0; pr<2; ++pr){
      const int rt = pr ? rt1 : rt0;
      floatx4 a2 = pr ? acc21 : acc20;
      float zp   = pr ? zp1 : zp0;
      float zr = zp + __shfl_xor(zp,16); zr += __shfl_xor(zr,32);
      float zi = __builtin_amdgcn_rcpf(zr);
      float pc0[4], pc1[4];
      #pragma unroll
      for (int r=0; r<4; ++r){
        float ziR = __shfl(zi, kg*4+r);
        float o  = fmaf(a2[r], ziR, b1v);
        float oe = (o>0.f) ? o : (__expf(o)-1.f);   // elu
        pc0[r] = red16(oe*w2c0);
        pc1[r] = red16(oe*w2c1);
      }
      if (of==0){
        #pragma unroll
        for (int r=0; r<4; ++r){
          int i = rt*16 + kg*4 + r;
          h2p[lhd*128 + i] = make_float2(pc0[r], pc1[r]);
        }
      }
    }
  }
  __syncthreads();

  // ---------- block-partial h2 (sum over this block's 4 heads) -> ws ----------
  if (t < 256){
    const int jn = t>>1, cc = t&1;
    float hv = 0.f;
    #pragma unroll
    for (int hd2=0; hd2<4; ++hd2){
      float2 p = h2p[hd2*128+jn];
      hv += cc ? p.y : p.x;
    }
    ws_h2[(size_t)blk*256 + t] = hv;
  }
}

// ---- tail: layer-2 ego-row softmax + log_softmax + mean over S ----
__global__ __launch_bounds__(256) void gat_tail(
    const float* __restrict__ ws_h2, const int* __restrict__ adj,
    const float* __restrict__ a_src2, const float* __restrict__ a_dst2,
    const float* __restrict__ b2, float* __restrict__ out)
{
  __shared__ float d2_l[128];
  __shared__ float red[16];
  __shared__ float srcE;
  const int bb = blockIdx.x, t = threadIdx.x;
  const int jn = t>>1, cc = t&1, lane = t&63, w = t>>6;
  const uint32_t bit = (adj[((size_t)bb*128+127)*128 + jn] != 0) ? 1u : 0u;
  float acc0=0.f, acc1=0.f;
  for (int s=0; s<4; ++s){
    float hv = ws_h2[(size_t)(s*256 + bb*2 + 0)*256 + t]
             + ws_h2[(size_t)(s*256 + bb*2 + 1)*256 + t];
    float th2 = fast_tanh(hv);
    float ps2 = th2*a_src2[s*2+cc];
    float pd2 = th2*a_dst2[s*2+cc];
    ps2 += __shfl_xor(ps2,1);
    pd2 += __shfl_xor(pd2,1);
    if (s) __syncthreads();                  // WAR on d2_l/srcE/red
    if (cc==0) d2_l[jn]=pd2;
    if (t==254) srcE=ps2;                    // ego node jn=127
    __syncthreads();
    float t0 = srcE + d2_l[jn];
    float lg = fmaxf(t0, 0.2f*t0);
    float v  = bit ? lg : -1e9f;
    float mloc = v;
    #pragma unroll
    for (int off=32; off>=1; off>>=1) mloc = fmaxf(mloc, __shfl_xor(mloc,off));
    if (lane==0) red[w]=mloc;
    __syncthreads();
    float M = fmaxf(fmaxf(red[0],red[1]), fmaxf(red[2],red[3]));
    float e2 = __expf(v-M);
    float vA = e2*hv;
    float vZ = (cc==0) ? e2 : 0.f;
    #pragma unroll
    for (int off=2; off<=32; off<<=1){ vA+=__shfl_xor(vA,off); vZ+=__shfl_xor(vZ,off); }
    if (lane==0){ red[4+w]=vA; red[12+w]=vZ; }
    if (lane==1){ red[8+w]=vA; }
    __syncthreads();
    if (t==0){
      float S0 = red[4]+red[5]+red[6]+red[7];
      float S1 = red[8]+red[9]+red[10]+red[11];
      float Z  = red[12]+red[13]+red[14]+red[15];
      float o0 = S0/Z + b2[0];
      float o1 = S1/Z + b2[1];
      float mm = fmaxf(o0,o1);
      float lse = mm + logf(__expf(o0-mm)+__expf(o1-mm));
      acc0 += 0.25f*(o0 - lse);
      acc1 += 0.25f*(o1 - lse);
    }
  }
  if (t==0){ out[bb*2+0]=acc0; out[bb*2+1]=acc1; }
}

extern "C" void kernel_launch(void* const* d_in, const int* in_sizes, int n_in,
                              void* d_out, int out_size, void* d_ws, size_t ws_size,
                              hipStream_t stream) {
  const float* x      = (const float*)d_in[0];
  const float* emb    = (const float*)d_in[1];
  const int*   adj    = (const int*)d_in[2];
  const float* w1     = (const float*)d_in[3];
  const float* a_src1 = (const float*)d_in[4];
  const float* a_dst1 = (const float*)d_in[5];
  const float* b1     = (const float*)d_in[6];
  const float* w2     = (const float*)d_in[7];
  const float* a_src2 = (const float*)d_in[8];
  const float* a_dst2 = (const float*)d_in[9];
  const float* b2     = (const float*)d_in[10];

  float* ws_h2 = (float*)d_ws;   // 1024 blocks x 256 floats = 1 MB

  gat_fused<<<dim3(1024), dim3(512), 0, stream>>>(x, emb, adj, w1, a_src1, a_dst1,
                                                  b1, w2, ws_h2);
  gat_tail<<<dim3(128), dim3(256), 0, stream>>>(ws_h2, adj, a_src2, a_dst2, b2,
                                                (float*)d_out);
}

// Round 10
// 129.736 us; speedup vs baseline: 2.0000x; 1.0576x over previous
//
#include <hip/hip_runtime.h>
#include <stdint.h>
#include <math.h>

typedef __attribute__((ext_vector_type(8))) short short8;
typedef __attribute__((ext_vector_type(4))) float floatx4;

// ---------------- LDS layout (26624 B -> 3 blocks/CU at 6 waves/SIMD) ----------------
#define L_HF    0        // 16384: W1 B-frags, then h B-frags: [ct(4)][ks(4)][lane(64)] x 16B
#define L_SRC   16384    // 2048 : att_src [4][128] f32 (pre-scaled by log2e)
#define L_DST   18432    // 2048 : att_dst [4][128] f32 (pre-scaled by log2e)
#define L_MASK  20480    // 2048 : mask bits [128 rows][16 B]
#define L_H2P   22528    // 4096 : layer-2 partials float2[4 heads][128 nodes]
#define L_SIZE  26624

union F8 { short8 s8; uint32_t u[4]; };

#if __has_builtin(__builtin_amdgcn_exp2f)
#define EXP2F __builtin_amdgcn_exp2f
#else
#define EXP2F exp2f
#endif
#define LOG2E 1.4426950408889634f

__device__ __forceinline__ uint32_t packbf(float a, float b){
  uint32_t ua = __float_as_uint(a), ub = __float_as_uint(b);
  uint32_t ra = (ua + 0x7fffu + ((ua>>16)&1u)) >> 16;   // RNE bf16
  uint32_t rb = (ub + 0x7fffu + ((ub>>16)&1u)) >> 16;
  return ra | (rb<<16);
}
// truncation pack (1 inst): low16 = hi16(a), high16 = hi16(b)
__device__ __forceinline__ uint32_t packbf_t(float a, float b){
  return __builtin_amdgcn_perm(__float_as_uint(b), __float_as_uint(a), 0x07060302u);
}
__device__ __forceinline__ float fast_tanh(float x){
  float e = __expf(2.f*x);
  return 1.f - 2.f*__builtin_amdgcn_rcpf(e + 1.f);
}
// sum over the 16-lane DPP row via row_ror — result valid in ALL lanes. Pure VALU.
__device__ __forceinline__ float red16(float x){
  x += __int_as_float(__builtin_amdgcn_update_dpp(0, __float_as_int(x), 0x128, 0xf, 0xf, true)); // row_ror:8
  x += __int_as_float(__builtin_amdgcn_update_dpp(0, __float_as_int(x), 0x124, 0xf, 0xf, true)); // row_ror:4
  x += __int_as_float(__builtin_amdgcn_update_dpp(0, __float_as_int(x), 0x122, 0xf, 0xf, true)); // row_ror:2
  x += __int_as_float(__builtin_amdgcn_update_dpp(0, __float_as_int(x), 0x121, 0xf, 0xf, true)); // row_ror:1
  return x;
}

// ---- fused GAT: one block per (s, b, head-half), 8 waves ----
// launch_bounds (512,6): 85-VGPR budget so the paired phase-2 chains fit w/o spill.
__global__ __launch_bounds__(512,6) void gat_fused(
    const float* __restrict__ x,  const float* __restrict__ emb,
    const int* __restrict__ adj,  const float* __restrict__ w1,
    const float* __restrict__ a_src1, const float* __restrict__ a_dst1,
    const float* __restrict__ b1, const float* __restrict__ w2,
    float* __restrict__ ws_h2)
{
  __shared__ __align__(16) char smem[L_SIZE];
  char*     hf    = smem + L_HF;
  uint32_t* hf_u  = (uint32_t*)(smem + L_HF);
  float*    src_l = (float*)(smem + L_SRC);
  float*    dst_l = (float*)(smem + L_DST);
  uint32_t* mask_l= (uint32_t*)(smem + L_MASK);
  const uint4* mask4 = (const uint4*)(smem + L_MASK);
  float2*   h2p   = (float2*)(smem + L_H2P);

  const int t    = threadIdx.x;
  const int blk  = blockIdx.x;
  const int s    = blk >> 8;
  const int bb   = (blk & 255) >> 1;
  const int half = blk & 1;
  const int lane = t & 63, w = t >> 6;
  const int of = lane & 15, kg = lane >> 4;

  // ---------- Phase 0a: A-frags direct from global (rows w*16+of) ----------
  const int arow = w*16 + of;
  const float* xrow = x   + ((size_t)bb*128 + arow)*64;
  const float* erow = emb + ((size_t)bb*128 + arow)*64;
  short8 af[4];
  #pragma unroll
  for (int ks=0; ks<4; ++ks){
    int k = ks*32 + kg*8;
    const float* p = (k<64) ? (xrow+k) : (erow + (k-64));
    float4 f0 = *(const float4*)p, f1 = *(const float4*)(p+4);
    F8 fr;
    fr.u[0]=packbf(f0.x,f0.y); fr.u[1]=packbf(f0.z,f0.w);
    fr.u[2]=packbf(f1.x,f1.y); fr.u[3]=packbf(f1.z,f1.w);
    af[ks]=fr.s8;
  }

  // ---------- Phase 0b: stage this block's 4 heads of W1 as bf16 B-frags ----------
  {
    const float* w1s = w1 + (size_t)s*16384 + half*8192;  // 4 heads x 128 x 16
    #pragma unroll
    for (int r=0; r<2; ++r){
      int q = t + r*512;                     // 0..1023 = (ct*4+ks)*64 + qlane
      int ql = q & 63, ks = (q>>6)&3, ct = q>>8;
      const float* wp = w1s + ct*2048 + (ks*32 + (ql>>4)*8)*16 + (ql&15);
      F8 fr;
      fr.u[0]=packbf(wp[0],  wp[16]);
      fr.u[1]=packbf(wp[32], wp[48]);
      fr.u[2]=packbf(wp[64], wp[80]);
      fr.u[3]=packbf(wp[96], wp[112]);
      *(short8*)(hf + ((ct*4+ks)*64 + ql)*16) = fr.s8;
    }
  }

  // ---------- Phase 0c: adjacency ballot -> mask bits (wave w: rows w*16..+15) ----------
  {
    const int* adjb = adj + (size_t)bb*16384;
    #pragma unroll 4
    for (int rr=0; rr<16; ++rr){
      const int row = w*16 + rr;
      const int* ar = adjb + row*128;
      uint64_t m0 = __ballot(ar[lane] != 0);
      uint64_t m1 = __ballot(ar[64+lane] != 0);
      if (lane == 0)
        ((uint4*)mask_l)[row] = make_uint4((uint32_t)m0,(uint32_t)(m0>>32),
                                           (uint32_t)m1,(uint32_t)(m1>>32));
    }
  }
  __syncthreads();

  // ---------- Phase 1: h = x0 @ W1 via MFMA ----------
  floatx4 acc[4];
  #pragma unroll
  for (int ct=0; ct<4; ++ct) acc[ct]=(floatx4){0.f,0.f,0.f,0.f};
  #pragma unroll
  for (int ct=0; ct<4; ++ct)
    #pragma unroll
    for (int ks=0; ks<4; ++ks){
      short8 bfr = *(const short8*)(hf + ((ct*4+ks)*64 + lane)*16);
      acc[ct] = __builtin_amdgcn_mfma_f32_16x16x32_bf16(af[ks], bfr, acc[ct], 0,0,0);
    }
  __syncthreads();                            // all W1-frag reads done before h overwrite

  // epilogue: tanh -> att partials (x log2e) via DPP row-reduce; h -> LDS in B-frag order
  const int ks_h = w>>1, kgp = (w&1)*2 + (kg>>1), vv = (kg&1)*2;
  #pragma unroll
  for (int ct=0; ct<4; ++ct){
    const int ghd = half*4 + ct;
    float asv = a_src1[s*128 + ghd*16 + of] * LOG2E;
    float adv = a_dst1[s*128 + ghd*16 + of] * LOG2E;
    float ps[4], pd[4];
    #pragma unroll
    for (int r=0; r<4; ++r){
      float th = fast_tanh(acc[ct][r]);
      ps[r] = red16(th*asv); pd[r] = red16(th*adv);
    }
    if (of==0){
      #pragma unroll
      for (int r=0; r<4; ++r){
        int i = w*16 + kg*4 + r;
        src_l[ct*128+i]=ps[r]; dst_l[ct*128+i]=pd[r];
      }
    }
    uint32_t p0 = packbf(acc[ct][0], acc[ct][1]);
    uint32_t p1 = packbf(acc[ct][2], acc[ct][3]);
    uint32_t* dsth = hf_u + ((ct*4+ks_h)*64 + kgp*16 + of)*4 + vv;
    *(uint2*)dsth = make_uint2(p0, p1);
  }
  __syncthreads();

  // ---------- Phase 2: softmax(lrelu(src+dst)) @ h, fused elu + W2 dot ----------
  // row-tiles paired 2-at-a-time: dst loaded once per ks per pair, 2 independent
  // exp->pack->MFMA chains for ILP. hbk loaded per-ks.
  const int lhd = w >> 1;                     // 2 waves per head
  const int ghd = half*4 + lhd;
  const int rtb = (w&1)*4;                    // this wave's row-tile base
  float b1v  = b1[of];
  float w2c0 = w2[s*256 + (ghd*16+of)*2 + 0];
  float w2c1 = w2[s*256 + (ghd*16+of)*2 + 1];

  #pragma unroll
  for (int pp=0; pp<2; ++pp){
    const int rt0 = rtb + pp*2, rt1 = rt0 + 1;
    const int im0 = rt0*16 + of, im1 = rt1*16 + of;
    float srcv0 = src_l[lhd*128 + im0];
    float srcv1 = src_l[lhd*128 + im1];
    uint4 mrow0 = mask4[im0];
    uint4 mrow1 = mask4[im1];
    floatx4 acc20 = (floatx4){0.f,0.f,0.f,0.f};
    floatx4 acc21 = (floatx4){0.f,0.f,0.f,0.f};
    float zp0 = 0.f, zp1 = 0.f;
    #pragma unroll
    for (int ks=0; ks<4; ++ks){
      const float* dp = dst_l + lhd*128 + ks*32 + kg*8;
      float4 d0 = *(const float4*)dp, d1 = *(const float4*)(dp+4);
      short8 hbk = *(const short8*)(hf + ((lhd*4+ks)*64 + lane)*16);
      uint32_t mw0 = (ks==0)?mrow0.x:(ks==1)?mrow0.y:(ks==2)?mrow0.z:mrow0.w;
      uint32_t mw1 = (ks==0)?mrow1.x:(ks==1)?mrow1.y:(ks==2)?mrow1.z:mrow1.w;
      uint32_t mb0 = mw0 >> (kg*8);
      uint32_t mb1 = mw1 >> (kg*8);
      float dj[8] = {d0.x,d0.y,d0.z,d0.w,d1.x,d1.y,d1.z,d1.w};
      float e0[8], e1[8];
      #pragma unroll
      for (int jj=0; jj<8; ++jj){
        float t0 = srcv0 + dj[jj];
        float t1 = srcv1 + dj[jj];
        float l0 = fmaxf(t0, 0.2f*t0);
        float l1 = fmaxf(t1, 0.2f*t1);
        float v0 = EXP2F(l0);
        float v1 = EXP2F(l1);
        v0 = ((mb0>>jj)&1u) ? v0 : 0.f;
        v1 = ((mb1>>jj)&1u) ? v1 : 0.f;
        e0[jj]=v0; zp0 += v0;
        e1[jj]=v1; zp1 += v1;
      }
      F8 fr0, fr1;
      fr0.u[0]=packbf_t(e0[0],e0[1]); fr0.u[1]=packbf_t(e0[2],e0[3]);
      fr0.u[2]=packbf_t(e0[4],e0[5]); fr0.u[3]=packbf_t(e0[6],e0[7]);
      fr1.u[0]=packbf_t(e1[0],e1[1]); fr1.u[1]=packbf_t(e1[2],e1[3]);
      fr1.u[2]=packbf_t(e1[4],e1[5]); fr1.u[3]=packbf_t(e1[6],e1[7]);
      acc20 = __builtin_amdgcn_mfma_f32_16x16x32_bf16(fr0.s8, hbk, acc20, 0,0,0);
      acc21 = __builtin_amdgcn_mfma_f32_16x16x32_bf16(fr1.s8, hbk, acc21, 0,0,0);
    }
    #pragma unroll
    for (int pr=0; pr<2; ++pr){
      const int rt = pr ? rt1 : rt0;
      floatx4 a2 = pr ? acc21 : acc20;
      float zp   = pr ? zp1 : zp0;
      float zr = zp + __shfl_xor(zp,16); zr += __shfl_xor(zr,32);
      float zi = __builtin_amdgcn_rcpf(zr);
      float pc0[4], pc1[4];
      #pragma unroll
      for (int r=0; r<4; ++r){
        float ziR = __shfl(zi, kg*4+r);
        float o  = fmaf(a2[r], ziR, b1v);
        float oe = (o>0.f) ? o : (__expf(o)-1.f);   // elu
        pc0[r] = red16(oe*w2c0);
        pc1[r] = red16(oe*w2c1);
      }
      if (of==0){
        #pragma unroll
        for (int r=0; r<4; ++r){
          int i = rt*16 + kg*4 + r;
          h2p[lhd*128 + i] = make_float2(pc0[r], pc1[r]);
        }
      }
    }
  }
  __syncthreads();

  // ---------- block-partial h2 (sum over this block's 4 heads) -> ws ----------
  if (t < 256){
    const int jn = t>>1, cc = t&1;
    float hv = 0.f;
    #pragma unroll
    for (int hd2=0; hd2<4; ++hd2){
      float2 p = h2p[hd2*128+jn];
      hv += cc ? p.y : p.x;
    }
    ws_h2[(size_t)blk*256 + t] = hv;
  }
}

// ---- tail: layer-2 ego-row softmax + log_softmax + mean over S ----
__global__ __launch_bounds__(256) void gat_tail(
    const float* __restrict__ ws_h2, const int* __restrict__ adj,
    const float* __restrict__ a_src2, const float* __restrict__ a_dst2,
    const float* __restrict__ b2, float* __restrict__ out)
{
  __shared__ float d2_l[128];
  __shared__ float red[16];
  __shared__ float srcE;
  const int bb = blockIdx.x, t = threadIdx.x;
  const int jn = t>>1, cc = t&1, lane = t&63, w = t>>6;
  const uint32_t bit = (adj[((size_t)bb*128+127)*128 + jn] != 0) ? 1u : 0u;
  float acc0=0.f, acc1=0.f;
  for (int s=0; s<4; ++s){
    float hv = ws_h2[(size_t)(s*256 + bb*2 + 0)*256 + t]
             + ws_h2[(size_t)(s*256 + bb*2 + 1)*256 + t];
    float th2 = fast_tanh(hv);
    float ps2 = th2*a_src2[s*2+cc];
    float pd2 = th2*a_dst2[s*2+cc];
    ps2 += __shfl_xor(ps2,1);
    pd2 += __shfl_xor(pd2,1);
    if (s) __syncthreads();                  // WAR on d2_l/srcE/red
    if (cc==0) d2_l[jn]=pd2;
    if (t==254) srcE=ps2;                    // ego node jn=127
    __syncthreads();
    float t0 = srcE + d2_l[jn];
    float lg = fmaxf(t0, 0.2f*t0);
    float v  = bit ? lg : -1e9f;
    float mloc = v;
    #pragma unroll
    for (int off=32; off>=1; off>>=1) mloc = fmaxf(mloc, __shfl_xor(mloc,off));
    if (lane==0) red[w]=mloc;
    __syncthreads();
    float M = fmaxf(fmaxf(red[0],red[1]), fmaxf(red[2],red[3]));
    float e2 = __expf(v-M);
    float vA = e2*hv;
    float vZ = (cc==0) ? e2 : 0.f;
    #pragma unroll
    for (int off=2; off<=32; off<<=1){ vA+=__shfl_xor(vA,off); vZ+=__shfl_xor(vZ,off); }
    if (lane==0){ red[4+w]=vA; red[12+w]=vZ; }
    if (lane==1){ red[8+w]=vA; }
    __syncthreads();
    if (t==0){
      float S0 = red[4]+red[5]+red[6]+red[7];
      float S1 = red[8]+red[9]+red[10]+red[11];
      float Z  = red[12]+red[13]+red[14]+red[15];
      float o0 = S0/Z + b2[0];
      float o1 = S1/Z + b2[1];
      float mm = fmaxf(o0,o1);
      float lse = mm + logf(__expf(o0-mm)+__expf(o1-mm));
      acc0 += 0.25f*(o0 - lse);
      acc1 += 0.25f*(o1 - lse);
    }
  }
  if (t==0){ out[bb*2+0]=acc0; out[bb*2+1]=acc1; }
}

extern "C" void kernel_launch(void* const* d_in, const int* in_sizes, int n_in,
                              void* d_out, int out_size, void* d_ws, size_t ws_size,
                              hipStream_t stream) {
  const float* x      = (const float*)d_in[0];
  const float* emb    = (const float*)d_in[1];
  const int*   adj    = (const int*)d_in[2];
  const float* w1     = (const float*)d_in[3];
  const float* a_src1 = (const float*)d_in[4];
  const float* a_dst1 = (const float*)d_in[5];
  const float* b1     = (const float*)d_in[6];
  const float* w2     = (const float*)d_in[7];
  const float* a_src2 = (const float*)d_in[8];
  const float* a_dst2 = (const float*)d_in[9];
  const float* b2     = (const float*)d_in[10];

  float* ws_h2 = (float*)d_ws;   // 1024 blocks x 256 floats = 1 MB

  gat_fused<<<dim3(1024), dim3(512), 0, stream>>>(x, emb, adj, w1, a_src1, a_dst1,
                                                  b1, w2, ws_h2);
  gat_tail<<<dim3(128), dim3(256), 0, stream>>>(ws_h2, adj, a_src2, a_dst2, b2,
                                                (float*)d_out);
}

// Round 11
// 124.647 us; speedup vs baseline: 2.0817x; 1.0408x over previous
//
#include <hip/hip_runtime.h>
#include <stdint.h>
#include <math.h>

typedef __attribute__((ext_vector_type(8))) short short8;
typedef __attribute__((ext_vector_type(4))) float floatx4;

// ---------------- LDS layout (26624 B) ----------------
#define L_HF    0        // 16384: W1 B-frags, then h B-frags: [ct(4)][ks(4)][lane(64)] x 16B
#define L_SRC   16384    // 2048 : att_src [4][128] f32 (pre-scaled by log2e)
#define L_DST   18432    // 2048 : att_dst [4][128] f32 (pre-scaled by log2e)
#define L_MASK  20480    // 2048 : mask bits [128 rows][16 B]
#define L_H2P   22528    // 4096 : layer-2 partials float2[4 heads][128 nodes]
#define L_SIZE  26624

union F8 { short8 s8; uint32_t u[4]; };

#if __has_builtin(__builtin_amdgcn_exp2f)
#define EXP2F __builtin_amdgcn_exp2f
#else
#define EXP2F exp2f
#endif
#define LOG2E 1.4426950408889634f

__device__ __forceinline__ uint32_t packbf(float a, float b){
  uint32_t ua = __float_as_uint(a), ub = __float_as_uint(b);
  uint32_t ra = (ua + 0x7fffu + ((ua>>16)&1u)) >> 16;   // RNE bf16
  uint32_t rb = (ub + 0x7fffu + ((ub>>16)&1u)) >> 16;
  return ra | (rb<<16);
}
// truncation pack (1 inst): low16 = hi16(a), high16 = hi16(b)
__device__ __forceinline__ uint32_t packbf_t(float a, float b){
  return __builtin_amdgcn_perm(__float_as_uint(b), __float_as_uint(a), 0x07060302u);
}
__device__ __forceinline__ float fast_tanh(float x){
  float e = __expf(2.f*x);
  return 1.f - 2.f*__builtin_amdgcn_rcpf(e + 1.f);
}
// masked exp2: returns exp2(l) if bit jj of mb set, else 0. Mask via sign-extend+and (2 VALU).
__device__ __forceinline__ float mexp2(float l, uint32_t mb, int jj){
  float e = EXP2F(l);
  int sm = ((int)(mb << (31-jj))) >> 31;     // 0 or 0xFFFFFFFF
  return __int_as_float(__float_as_int(e) & sm);
}
// sum over the 16-lane DPP row via row_ror — result valid in ALL lanes. Pure VALU.
__device__ __forceinline__ float red16(float x){
  x += __int_as_float(__builtin_amdgcn_update_dpp(0, __float_as_int(x), 0x128, 0xf, 0xf, true)); // row_ror:8
  x += __int_as_float(__builtin_amdgcn_update_dpp(0, __float_as_int(x), 0x124, 0xf, 0xf, true)); // row_ror:4
  x += __int_as_float(__builtin_amdgcn_update_dpp(0, __float_as_int(x), 0x122, 0xf, 0xf, true)); // row_ror:2
  x += __int_as_float(__builtin_amdgcn_update_dpp(0, __float_as_int(x), 0x121, 0xf, 0xf, true)); // row_ror:1
  return x;
}

// ---- fused GAT: one block per (s, b, head-half), 8 waves ----
__global__ __launch_bounds__(512,6) void gat_fused(
    const float* __restrict__ x,  const float* __restrict__ emb,
    const int* __restrict__ adj,  const float* __restrict__ w1,
    const float* __restrict__ a_src1, const float* __restrict__ a_dst1,
    const float* __restrict__ b1, const float* __restrict__ w2,
    float* __restrict__ ws_h2)
{
  __shared__ __align__(16) char smem[L_SIZE];
  char*     hf    = smem + L_HF;
  uint32_t* hf_u  = (uint32_t*)(smem + L_HF);
  float*    src_l = (float*)(smem + L_SRC);
  float*    dst_l = (float*)(smem + L_DST);
  uint32_t* mask_l= (uint32_t*)(smem + L_MASK);
  const uint4* mask4 = (const uint4*)(smem + L_MASK);
  float2*   h2p   = (float2*)(smem + L_H2P);

  const int t    = threadIdx.x;
  const int blk  = blockIdx.x;
  const int s    = blk >> 8;
  const int bb   = (blk & 255) >> 1;
  const int half = blk & 1;
  const int lane = t & 63, w = t >> 6;
  const int of = lane & 15, kg = lane >> 4;

  // ---------- Phase 0a: A-frags direct from global (rows w*16+of) ----------
  const int arow = w*16 + of;
  const float* xrow = x   + ((size_t)bb*128 + arow)*64;
  const float* erow = emb + ((size_t)bb*128 + arow)*64;
  short8 af[4];
  #pragma unroll
  for (int ks=0; ks<4; ++ks){
    int k = ks*32 + kg*8;
    const float* p = (k<64) ? (xrow+k) : (erow + (k-64));
    float4 f0 = *(const float4*)p, f1 = *(const float4*)(p+4);
    F8 fr;
    fr.u[0]=packbf(f0.x,f0.y); fr.u[1]=packbf(f0.z,f0.w);
    fr.u[2]=packbf(f1.x,f1.y); fr.u[3]=packbf(f1.z,f1.w);
    af[ks]=fr.s8;
  }

  // ---------- Phase 0b: stage this block's 4 heads of W1 as bf16 B-frags ----------
  {
    const float* w1s = w1 + (size_t)s*16384 + half*8192;  // 4 heads x 128 x 16
    #pragma unroll
    for (int r=0; r<2; ++r){
      int q = t + r*512;                     // 0..1023 = (ct*4+ks)*64 + qlane
      int ql = q & 63, ks = (q>>6)&3, ct = q>>8;
      const float* wp = w1s + ct*2048 + (ks*32 + (ql>>4)*8)*16 + (ql&15);
      F8 fr;
      fr.u[0]=packbf(wp[0],  wp[16]);
      fr.u[1]=packbf(wp[32], wp[48]);
      fr.u[2]=packbf(wp[64], wp[80]);
      fr.u[3]=packbf(wp[96], wp[112]);
      *(short8*)(hf + ((ct*4+ks)*64 + ql)*16) = fr.s8;
    }
  }

  // ---------- Phase 0c: adjacency ballot -> mask bits (wave w: rows w*16..+15) ----------
  {
    const int* adjb = adj + (size_t)bb*16384;
    #pragma unroll 4
    for (int rr=0; rr<16; ++rr){
      const int row = w*16 + rr;
      const int* ar = adjb + row*128;
      uint64_t m0 = __ballot(ar[lane] != 0);
      uint64_t m1 = __ballot(ar[64+lane] != 0);
      if (lane == 0)
        ((uint4*)mask_l)[row] = make_uint4((uint32_t)m0,(uint32_t)(m0>>32),
                                           (uint32_t)m1,(uint32_t)(m1>>32));
    }
  }
  __syncthreads();

  // ---------- Phase 1: h = x0 @ W1 via MFMA ----------
  floatx4 acc[4];
  #pragma unroll
  for (int ct=0; ct<4; ++ct) acc[ct]=(floatx4){0.f,0.f,0.f,0.f};
  #pragma unroll
  for (int ct=0; ct<4; ++ct)
    #pragma unroll
    for (int ks=0; ks<4; ++ks){
      short8 bfr = *(const short8*)(hf + ((ct*4+ks)*64 + lane)*16);
      acc[ct] = __builtin_amdgcn_mfma_f32_16x16x32_bf16(af[ks], bfr, acc[ct], 0,0,0);
    }
  __syncthreads();                            // all W1-frag reads done before h overwrite

  // epilogue: tanh -> att partials (x log2e) via DPP row-reduce; h -> LDS in B-frag order
  const int ks_h = w>>1, kgp = (w&1)*2 + (kg>>1), vv = (kg&1)*2;
  #pragma unroll
  for (int ct=0; ct<4; ++ct){
    const int ghd = half*4 + ct;
    float asv = a_src1[s*128 + ghd*16 + of] * LOG2E;
    float adv = a_dst1[s*128 + ghd*16 + of] * LOG2E;
    float ps[4], pd[4];
    #pragma unroll
    for (int r=0; r<4; ++r){
      float th = fast_tanh(acc[ct][r]);
      ps[r] = red16(th*asv); pd[r] = red16(th*adv);
    }
    if (of==0){
      #pragma unroll
      for (int r=0; r<4; ++r){
        int i = w*16 + kg*4 + r;
        src_l[ct*128+i]=ps[r]; dst_l[ct*128+i]=pd[r];
      }
    }
    uint32_t p0 = packbf(acc[ct][0], acc[ct][1]);
    uint32_t p1 = packbf(acc[ct][2], acc[ct][3]);
    uint32_t* dsth = hf_u + ((ct*4+ks_h)*64 + kgp*16 + of)*4 + vv;
    *(uint2*)dsth = make_uint2(p0, p1);
  }
  __syncthreads();

  // ---------- Phase 2: softmax(lrelu(src+dst)) @ h, fused elu + W2 dot ----------
  // Paired row-tiles (2 independent chains). z via MFMA-with-ones on the idle
  // matrix pipe: acc_z[r] = row-sum of P in exactly the C-slot where it's used
  // (row kg*4+r) -> no zp adds, no z shuffles.
  const int lhd = w >> 1;                     // 2 waves per head
  const int ghd = half*4 + lhd;
  const int rtb = (w&1)*4;                    // this wave's row-tile base
  float b1v  = b1[of];
  float w2c0 = w2[s*256 + (ghd*16+of)*2 + 0];
  float w2c1 = w2[s*256 + (ghd*16+of)*2 + 1];
  F8 onesf;                                   // bf16 1.0 x8
  onesf.u[0]=0x3F803F80u; onesf.u[1]=0x3F803F80u;
  onesf.u[2]=0x3F803F80u; onesf.u[3]=0x3F803F80u;

  #pragma unroll
  for (int pp=0; pp<2; ++pp){
    const int rt0 = rtb + pp*2, rt1 = rt0 + 1;
    const int im0 = rt0*16 + of, im1 = rt1*16 + of;
    float srcv0 = src_l[lhd*128 + im0];
    float srcv1 = src_l[lhd*128 + im1];
    uint4 mrow0 = mask4[im0];
    uint4 mrow1 = mask4[im1];
    floatx4 acc20 = (floatx4){0.f,0.f,0.f,0.f};
    floatx4 acc21 = (floatx4){0.f,0.f,0.f,0.f};
    floatx4 accz0 = (floatx4){0.f,0.f,0.f,0.f};
    floatx4 accz1 = (floatx4){0.f,0.f,0.f,0.f};
    #pragma unroll
    for (int ks=0; ks<4; ++ks){
      const float* dp = dst_l + lhd*128 + ks*32 + kg*8;
      float4 d0 = *(const float4*)dp, d1 = *(const float4*)(dp+4);
      short8 hbk = *(const short8*)(hf + ((lhd*4+ks)*64 + lane)*16);
      uint32_t mw0 = (ks==0)?mrow0.x:(ks==1)?mrow0.y:(ks==2)?mrow0.z:mrow0.w;
      uint32_t mw1 = (ks==0)?mrow1.x:(ks==1)?mrow1.y:(ks==2)?mrow1.z:mrow1.w;
      uint32_t mb0 = mw0 >> (kg*8);
      uint32_t mb1 = mw1 >> (kg*8);
      float dj[8] = {d0.x,d0.y,d0.z,d0.w,d1.x,d1.y,d1.z,d1.w};
      F8 fr0, fr1;
      #pragma unroll
      for (int jp=0; jp<4; ++jp){
        const int j0 = 2*jp, j1 = 2*jp+1;
        float ta0 = srcv0 + dj[j0], ta1 = srcv0 + dj[j1];
        float tb0 = srcv1 + dj[j0], tb1 = srcv1 + dj[j1];
        float la0 = fmaxf(ta0, 0.2f*ta0), la1 = fmaxf(ta1, 0.2f*ta1);
        float lb0 = fmaxf(tb0, 0.2f*tb0), lb1 = fmaxf(tb1, 0.2f*tb1);
        float ea0 = mexp2(la0, mb0, j0), ea1 = mexp2(la1, mb0, j1);
        float eb0 = mexp2(lb0, mb1, j0), eb1 = mexp2(lb1, mb1, j1);
        fr0.u[jp] = packbf_t(ea0, ea1);
        fr1.u[jp] = packbf_t(eb0, eb1);
      }
      acc20 = __builtin_amdgcn_mfma_f32_16x16x32_bf16(fr0.s8, hbk,      acc20, 0,0,0);
      accz0 = __builtin_amdgcn_mfma_f32_16x16x32_bf16(fr0.s8, onesf.s8, accz0, 0,0,0);
      acc21 = __builtin_amdgcn_mfma_f32_16x16x32_bf16(fr1.s8, hbk,      acc21, 0,0,0);
      accz1 = __builtin_amdgcn_mfma_f32_16x16x32_bf16(fr1.s8, onesf.s8, accz1, 0,0,0);
    }
    #pragma unroll
    for (int pr=0; pr<2; ++pr){
      const int rt = pr ? rt1 : rt0;
      floatx4 a2 = pr ? acc21 : acc20;
      floatx4 az = pr ? accz1 : accz0;
      float pc0[4], pc1[4];
      #pragma unroll
      for (int r=0; r<4; ++r){
        float zi = __builtin_amdgcn_rcpf(az[r]);    // z for row kg*4+r, in-slot
        float o  = fmaf(a2[r], zi, b1v);
        float oe = (o>0.f) ? o : (__expf(o)-1.f);   // elu
        pc0[r] = red16(oe*w2c0);
        pc1[r] = red16(oe*w2c1);
      }
      if (of==0){
        #pragma unroll
        for (int r=0; r<4; ++r){
          int i = rt*16 + kg*4 + r;
          h2p[lhd*128 + i] = make_float2(pc0[r], pc1[r]);
        }
      }
    }
  }
  __syncthreads();

  // ---------- block-partial h2 (sum over this block's 4 heads) -> ws ----------
  if (t < 256){
    const int jn = t>>1, cc = t&1;
    float hv = 0.f;
    #pragma unroll
    for (int hd2=0; hd2<4; ++hd2){
      float2 p = h2p[hd2*128+jn];
      hv += cc ? p.y : p.x;
    }
    ws_h2[(size_t)blk*256 + t] = hv;
  }
}

// ---- tail: layer-2 ego-row softmax + log_softmax + mean over S ----
__global__ __launch_bounds__(256) void gat_tail(
    const float* __restrict__ ws_h2, const int* __restrict__ adj,
    const float* __restrict__ a_src2, const float* __restrict__ a_dst2,
    const float* __restrict__ b2, float* __restrict__ out)
{
  __shared__ float d2_l[128];
  __shared__ float red[16];
  __shared__ float srcE;
  const int bb = blockIdx.x, t = threadIdx.x;
  const int jn = t>>1, cc = t&1, lane = t&63, w = t>>6;
  const uint32_t bit = (adj[((size_t)bb*128+127)*128 + jn] != 0) ? 1u : 0u;
  float acc0=0.f, acc1=0.f;
  for (int s=0; s<4; ++s){
    float hv = ws_h2[(size_t)(s*256 + bb*2 + 0)*256 + t]
             + ws_h2[(size_t)(s*256 + bb*2 + 1)*256 + t];
    float th2 = fast_tanh(hv);
    float ps2 = th2*a_src2[s*2+cc];
    float pd2 = th2*a_dst2[s*2+cc];
    ps2 += __shfl_xor(ps2,1);
    pd2 += __shfl_xor(pd2,1);
    if (s) __syncthreads();                  // WAR on d2_l/srcE/red
    if (cc==0) d2_l[jn]=pd2;
    if (t==254) srcE=ps2;                    // ego node jn=127
    __syncthreads();
    float t0 = srcE + d2_l[jn];
    float lg = fmaxf(t0, 0.2f*t0);
    float v  = bit ? lg : -1e9f;
    float mloc = v;
    #pragma unroll
    for (int off=32; off>=1; off>>=1) mloc = fmaxf(mloc, __shfl_xor(mloc,off));
    if (lane==0) red[w]=mloc;
    __syncthreads();
    float M = fmaxf(fmaxf(red[0],red[1]), fmaxf(red[2],red[3]));
    float e2 = __expf(v-M);
    float vA = e2*hv;
    float vZ = (cc==0) ? e2 : 0.f;
    #pragma unroll
    for (int off=2; off<=32; off<<=1){ vA+=__shfl_xor(vA,off); vZ+=__shfl_xor(vZ,off); }
    if (lane==0){ red[4+w]=vA; red[12+w]=vZ; }
    if (lane==1){ red[8+w]=vA; }
    __syncthreads();
    if (t==0){
      float S0 = red[4]+red[5]+red[6]+red[7];
      float S1 = red[8]+red[9]+red[10]+red[11];
      float Z  = red[12]+red[13]+red[14]+red[15];
      float o0 = S0/Z + b2[0];
      float o1 = S1/Z + b2[1];
      float mm = fmaxf(o0,o1);
      float lse = mm + logf(__expf(o0-mm)+__expf(o1-mm));
      acc0 += 0.25f*(o0 - lse);
      acc1 += 0.25f*(o1 - lse);
    }
  }
  if (t==0){ out[bb*2+0]=acc0; out[bb*2+1]=acc1; }
}

extern "C" void kernel_launch(void* const* d_in, const int* in_sizes, int n_in,
                              void* d_out, int out_size, void* d_ws, size_t ws_size,
                              hipStream_t stream) {
  const float* x      = (const float*)d_in[0];
  const float* emb    = (const float*)d_in[1];
  const int*   adj    = (const int*)d_in[2];
  const float* w1     = (const float*)d_in[3];
  const float* a_src1 = (const float*)d_in[4];
  const float* a_dst1 = (const float*)d_in[5];
  const float* b1     = (const float*)d_in[6];
  const float* w2     = (const float*)d_in[7];
  const float* a_src2 = (const float*)d_in[8];
  const float* a_dst2 = (const float*)d_in[9];
  const float* b2     = (const float*)d_in[10];

  float* ws_h2 = (float*)d_ws;   // 1024 blocks x 256 floats = 1 MB

  gat_fused<<<dim3(1024), dim3(512), 0, stream>>>(x, emb, adj, w1, a_src1, a_dst1,
                                                  b1, w2, ws_h2);
  gat_tail<<<dim3(128), dim3(256), 0, stream>>>(ws_h2, adj, a_src2, a_dst2, b2,
                                                (float*)d_out);
}

// Round 12
// 122.608 us; speedup vs baseline: 2.1163x; 1.0166x over previous
//
#include <hip/hip_runtime.h>
#include <stdint.h>
#include <math.h>

typedef __attribute__((ext_vector_type(8))) short short8;
typedef __attribute__((ext_vector_type(4))) float floatx4;

// ---------------- LDS layout (26624 B) ----------------
#define L_HF    0        // 16384: W1 B-frags, then h B-frags: [ct(4)][ks(4)][lane(64)] x 16B
#define L_SRC   16384    // 2048 : att_src [4][128] f32 (pre-scaled by log2e)
#define L_DST   18432    // 2048 : att_dst [4][128] f32 (pre-scaled by log2e)
#define L_MASK  20480    // 2048 : mask bits [128 rows][16 B]
#define L_H2P   22528    // 4096 : layer-2 partials float2[4 heads][128 nodes]
#define L_SIZE  26624

#define WS_H2_BYTES   (1024*256*4)   // 1 MB
// mask_ws lives after ws_h2: 128 bb x 512 u32 = 256 KB

union F8 { short8 s8; uint32_t u[4]; };

#if __has_builtin(__builtin_amdgcn_exp2f)
#define EXP2F __builtin_amdgcn_exp2f
#else
#define EXP2F exp2f
#endif
#define LOG2E  1.4426950408889634f
#define LOG2E2 2.8853900817779268f

__device__ __forceinline__ uint32_t packbf(float a, float b){
  uint32_t ua = __float_as_uint(a), ub = __float_as_uint(b);
  uint32_t ra = (ua + 0x7fffu + ((ua>>16)&1u)) >> 16;   // RNE bf16
  uint32_t rb = (ub + 0x7fffu + ((ub>>16)&1u)) >> 16;
  return ra | (rb<<16);
}
// truncation pack (1 inst): low16 = hi16(a), high16 = hi16(b)
__device__ __forceinline__ uint32_t packbf_t(float a, float b){
  return __builtin_amdgcn_perm(__float_as_uint(b), __float_as_uint(a), 0x07060302u);
}
__device__ __forceinline__ float fast_tanh(float x){
  float e = EXP2F(LOG2E2*x);                 // e^(2x)
  return fmaf(-2.f, __builtin_amdgcn_rcpf(e + 1.f), 1.f);
}
// masked exp2: returns exp2(l) if bit jj of mb set, else 0 (sign-extend+and).
__device__ __forceinline__ float mexp2(float l, uint32_t mb, int jj){
  float e = EXP2F(l);
  int sm = ((int)(mb << (31-jj))) >> 31;
  return __int_as_float(__float_as_int(e) & sm);
}
// sum over the 16-lane DPP row via row_ror — result valid in ALL lanes. Pure VALU.
__device__ __forceinline__ float red16(float x){
  x += __int_as_float(__builtin_amdgcn_update_dpp(0, __float_as_int(x), 0x128, 0xf, 0xf, true)); // row_ror:8
  x += __int_as_float(__builtin_amdgcn_update_dpp(0, __float_as_int(x), 0x124, 0xf, 0xf, true)); // row_ror:4
  x += __int_as_float(__builtin_amdgcn_update_dpp(0, __float_as_int(x), 0x122, 0xf, 0xf, true)); // row_ror:2
  x += __int_as_float(__builtin_amdgcn_update_dpp(0, __float_as_int(x), 0x121, 0xf, 0xf, true)); // row_ror:1
  return x;
}

// ---- prep: adjacency (b,n,n) int32 -> per-row 128-bit masks (dedup across s/half) ----
__global__ void mask_build(const int* __restrict__ adj, uint32_t* __restrict__ mask_ws) {
  const int t = threadIdx.x;
  const int row = blockIdx.x*4 + (t>>6);     // 4 waves/block, one row per wave
  const int lane = t & 63;
  const int* ar = adj + (size_t)row*128;
  uint64_t m0 = __ballot(ar[lane] != 0);
  uint64_t m1 = __ballot(ar[64+lane] != 0);
  if (lane == 0) {
    ((uint4*)mask_ws)[row] = make_uint4((uint32_t)m0, (uint32_t)(m0>>32),
                                        (uint32_t)m1, (uint32_t)(m1>>32));
  }
}

// ---- fused GAT: one block per (s, b, head-half), 8 waves ----
__global__ __launch_bounds__(512,6) void gat_fused(
    const float* __restrict__ x,  const float* __restrict__ emb,
    const float* __restrict__ w1,
    const float* __restrict__ a_src1, const float* __restrict__ a_dst1,
    const float* __restrict__ b1, const float* __restrict__ w2,
    const uint32_t* __restrict__ mask_ws, float* __restrict__ ws_h2)
{
  __shared__ __align__(16) char smem[L_SIZE];
  char*     hf    = smem + L_HF;
  uint32_t* hf_u  = (uint32_t*)(smem + L_HF);
  float*    src_l = (float*)(smem + L_SRC);
  float*    dst_l = (float*)(smem + L_DST);
  uint32_t* mask_l= (uint32_t*)(smem + L_MASK);
  const uint4* mask4 = (const uint4*)(smem + L_MASK);
  float2*   h2p   = (float2*)(smem + L_H2P);

  const int t    = threadIdx.x;
  const int blk  = blockIdx.x;
  const int s    = blk >> 8;
  const int bb   = (blk & 255) >> 1;
  const int half = blk & 1;
  const int lane = t & 63, w = t >> 6;
  const int of = lane & 15, kg = lane >> 4;

  // stage pre-packed mask rows (512 u32)
  mask_l[t] = mask_ws[(size_t)bb*512 + t];

  // ---------- Phase 0a: A-frags direct from global (rows w*16+of) ----------
  const int arow = w*16 + of;
  const float* xrow = x   + ((size_t)bb*128 + arow)*64;
  const float* erow = emb + ((size_t)bb*128 + arow)*64;
  short8 af[4];
  #pragma unroll
  for (int ks=0; ks<4; ++ks){
    int k = ks*32 + kg*8;
    const float* p = (k<64) ? (xrow+k) : (erow + (k-64));
    float4 f0 = *(const float4*)p, f1 = *(const float4*)(p+4);
    F8 fr;
    fr.u[0]=packbf_t(f0.x,f0.y); fr.u[1]=packbf_t(f0.z,f0.w);
    fr.u[2]=packbf_t(f1.x,f1.y); fr.u[3]=packbf_t(f1.z,f1.w);
    af[ks]=fr.s8;
  }

  // ---------- Phase 0b: stage this block's 4 heads of W1 as bf16 B-frags ----------
  {
    const float* w1s = w1 + (size_t)s*16384 + half*8192;  // 4 heads x 128 x 16
    #pragma unroll
    for (int r=0; r<2; ++r){
      int q = t + r*512;                     // 0..1023 = (ct*4+ks)*64 + qlane
      int ql = q & 63, ks = (q>>6)&3, ct = q>>8;
      const float* wp = w1s + ct*2048 + (ks*32 + (ql>>4)*8)*16 + (ql&15);
      F8 fr;
      fr.u[0]=packbf_t(wp[0],  wp[16]);
      fr.u[1]=packbf_t(wp[32], wp[48]);
      fr.u[2]=packbf_t(wp[64], wp[80]);
      fr.u[3]=packbf_t(wp[96], wp[112]);
      *(short8*)(hf + ((ct*4+ks)*64 + ql)*16) = fr.s8;
    }
  }
  __syncthreads();

  // ---------- Phase 1: h = x0 @ W1 via MFMA ----------
  floatx4 acc[4];
  #pragma unroll
  for (int ct=0; ct<4; ++ct) acc[ct]=(floatx4){0.f,0.f,0.f,0.f};
  #pragma unroll
  for (int ct=0; ct<4; ++ct)
    #pragma unroll
    for (int ks=0; ks<4; ++ks){
      short8 bfr = *(const short8*)(hf + ((ct*4+ks)*64 + lane)*16);
      acc[ct] = __builtin_amdgcn_mfma_f32_16x16x32_bf16(af[ks], bfr, acc[ct], 0,0,0);
    }
  __syncthreads();                            // all W1-frag reads done before h overwrite

  // epilogue: tanh -> att partials (x log2e) via DPP row-reduce; h -> LDS in B-frag order
  const int ks_h = w>>1, kgp = (w&1)*2 + (kg>>1), vv = (kg&1)*2;
  #pragma unroll
  for (int ct=0; ct<4; ++ct){
    const int ghd = half*4 + ct;
    float asv = a_src1[s*128 + ghd*16 + of] * LOG2E;
    float adv = a_dst1[s*128 + ghd*16 + of] * LOG2E;
    float ps[4], pd[4];
    #pragma unroll
    for (int r=0; r<4; ++r){
      float th = fast_tanh(acc[ct][r]);
      ps[r] = red16(th*asv); pd[r] = red16(th*adv);
    }
    if (of==0){
      #pragma unroll
      for (int r=0; r<4; ++r){
        int i = w*16 + kg*4 + r;
        src_l[ct*128+i]=ps[r]; dst_l[ct*128+i]=pd[r];
      }
    }
    uint32_t p0 = packbf(acc[ct][0], acc[ct][1]);
    uint32_t p1 = packbf(acc[ct][2], acc[ct][3]);
    uint32_t* dsth = hf_u + ((ct*4+ks_h)*64 + kgp*16 + of)*4 + vv;
    *(uint2*)dsth = make_uint2(p0, p1);
  }
  __syncthreads();

  // ---------- Phase 2: softmax(lrelu(src+dst)) @ h, fused elu + W2 dot ----------
  // Paired row-tiles, z via MFMA-with-ones (row-sum lands in the consuming C-slot).
  const int lhd = w >> 1;                     // 2 waves per head
  const int ghd = half*4 + lhd;
  const int rtb = (w&1)*4;                    // this wave's row-tile base
  float b1v  = b1[of];
  float w2c0 = w2[s*256 + (ghd*16+of)*2 + 0];
  float w2c1 = w2[s*256 + (ghd*16+of)*2 + 1];
  F8 onesf;                                   // bf16 1.0 x8
  onesf.u[0]=0x3F803F80u; onesf.u[1]=0x3F803F80u;
  onesf.u[2]=0x3F803F80u; onesf.u[3]=0x3F803F80u;

  #pragma unroll
  for (int pp=0; pp<2; ++pp){
    const int rt0 = rtb + pp*2, rt1 = rt0 + 1;
    const int im0 = rt0*16 + of, im1 = rt1*16 + of;
    float srcv0 = src_l[lhd*128 + im0];
    float srcv1 = src_l[lhd*128 + im1];
    uint4 mrow0 = mask4[im0];
    uint4 mrow1 = mask4[im1];
    floatx4 acc20 = (floatx4){0.f,0.f,0.f,0.f};
    floatx4 acc21 = (floatx4){0.f,0.f,0.f,0.f};
    floatx4 accz0 = (floatx4){0.f,0.f,0.f,0.f};
    floatx4 accz1 = (floatx4){0.f,0.f,0.f,0.f};
    #pragma unroll
    for (int ks=0; ks<4; ++ks){
      const float* dp = dst_l + lhd*128 + ks*32 + kg*8;
      float4 d0 = *(const float4*)dp, d1 = *(const float4*)(dp+4);
      short8 hbk = *(const short8*)(hf + ((lhd*4+ks)*64 + lane)*16);
      uint32_t mw0 = (ks==0)?mrow0.x:(ks==1)?mrow0.y:(ks==2)?mrow0.z:mrow0.w;
      uint32_t mw1 = (ks==0)?mrow1.x:(ks==1)?mrow1.y:(ks==2)?mrow1.z:mrow1.w;
      uint32_t mb0 = mw0 >> (kg*8);
      uint32_t mb1 = mw1 >> (kg*8);
      float dj[8] = {d0.x,d0.y,d0.z,d0.w,d1.x,d1.y,d1.z,d1.w};
      F8 fr0, fr1;
      #pragma unroll
      for (int jp=0; jp<4; ++jp){
        const int j0 = 2*jp, j1 = 2*jp+1;
        float ta0 = srcv0 + dj[j0], ta1 = srcv0 + dj[j1];
        float tb0 = srcv1 + dj[j0], tb1 = srcv1 + dj[j1];
        float la0 = fmaxf(ta0, 0.2f*ta0), la1 = fmaxf(ta1, 0.2f*ta1);
        float lb0 = fmaxf(tb0, 0.2f*tb0), lb1 = fmaxf(tb1, 0.2f*tb1);
        float ea0 = mexp2(la0, mb0, j0), ea1 = mexp2(la1, mb0, j1);
        float eb0 = mexp2(lb0, mb1, j0), eb1 = mexp2(lb1, mb1, j1);
        fr0.u[jp] = packbf_t(ea0, ea1);
        fr1.u[jp] = packbf_t(eb0, eb1);
      }
      acc20 = __builtin_amdgcn_mfma_f32_16x16x32_bf16(fr0.s8, hbk,      acc20, 0,0,0);
      accz0 = __builtin_amdgcn_mfma_f32_16x16x32_bf16(fr0.s8, onesf.s8, accz0, 0,0,0);
      acc21 = __builtin_amdgcn_mfma_f32_16x16x32_bf16(fr1.s8, hbk,      acc21, 0,0,0);
      accz1 = __builtin_amdgcn_mfma_f32_16x16x32_bf16(fr1.s8, onesf.s8, accz1, 0,0,0);
    }
    #pragma unroll
    for (int pr=0; pr<2; ++pr){
      const int rt = pr ? rt1 : rt0;
      floatx4 a2 = pr ? acc21 : acc20;
      floatx4 az = pr ? accz1 : accz0;
      float pc0[4], pc1[4];
      #pragma unroll
      for (int r=0; r<4; ++r){
        float zi = __builtin_amdgcn_rcpf(az[r]);    // z for row kg*4+r, in-slot
        float o  = fmaf(a2[r], zi, b1v);
        float oe = (o>0.f) ? o : (__expf(o)-1.f);   // elu
        pc0[r] = red16(oe*w2c0);
        pc1[r] = red16(oe*w2c1);
      }
      if (of==0){
        #pragma unroll
        for (int r=0; r<4; ++r){
          int i = rt*16 + kg*4 + r;
          h2p[lhd*128 + i] = make_float2(pc0[r], pc1[r]);
        }
      }
    }
  }
  __syncthreads();

  // ---------- block-partial h2 (sum over this block's 4 heads) -> ws ----------
  if (t < 256){
    const int jn = t>>1, cc = t&1;
    float hv = 0.f;
    #pragma unroll
    for (int hd2=0; hd2<4; ++hd2){
      float2 p = h2p[hd2*128+jn];
      hv += cc ? p.y : p.x;
    }
    ws_h2[(size_t)blk*256 + t] = hv;
  }
}

// ---- tail: layer-2 ego-row softmax + log_softmax + mean over S ----
__global__ __launch_bounds__(256) void gat_tail(
    const float* __restrict__ ws_h2, const int* __restrict__ adj,
    const float* __restrict__ a_src2, const float* __restrict__ a_dst2,
    const float* __restrict__ b2, float* __restrict__ out)
{
  __shared__ float d2_l[128];
  __shared__ float red[16];
  __shared__ float srcE;
  const int bb = blockIdx.x, t = threadIdx.x;
  const int jn = t>>1, cc = t&1, lane = t&63, w = t>>6;
  const uint32_t bit = (adj[((size_t)bb*128+127)*128 + jn] != 0) ? 1u : 0u;
  float acc0=0.f, acc1=0.f;
  for (int s=0; s<4; ++s){
    float hv = ws_h2[(size_t)(s*256 + bb*2 + 0)*256 + t]
             + ws_h2[(size_t)(s*256 + bb*2 + 1)*256 + t];
    float th2 = fast_tanh(hv);
    float ps2 = th2*a_src2[s*2+cc];
    float pd2 = th2*a_dst2[s*2+cc];
    ps2 += __shfl_xor(ps2,1);
    pd2 += __shfl_xor(pd2,1);
    if (s) __syncthreads();                  // WAR on d2_l/srcE/red
    if (cc==0) d2_l[jn]=pd2;
    if (t==254) srcE=ps2;                    // ego node jn=127
    __syncthreads();
    float t0 = srcE + d2_l[jn];
    float lg = fmaxf(t0, 0.2f*t0);
    float v  = bit ? lg : -1e9f;
    float mloc = v;
    #pragma unroll
    for (int off=32; off>=1; off>>=1) mloc = fmaxf(mloc, __shfl_xor(mloc,off));
    if (lane==0) red[w]=mloc;
    __syncthreads();
    float M = fmaxf(fmaxf(red[0],red[1]), fmaxf(red[2],red[3]));
    float e2 = __expf(v-M);
    float vA = e2*hv;
    float vZ = (cc==0) ? e2 : 0.f;
    #pragma unroll
    for (int off=2; off<=32; off<<=1){ vA+=__shfl_xor(vA,off); vZ+=__shfl_xor(vZ,off); }
    if (lane==0){ red[4+w]=vA; red[12+w]=vZ; }
    if (lane==1){ red[8+w]=vA; }
    __syncthreads();
    if (t==0){
      float S0 = red[4]+red[5]+red[6]+red[7];
      float S1 = red[8]+red[9]+red[10]+red[11];
      float Z  = red[12]+red[13]+red[14]+red[15];
      float o0 = S0/Z + b2[0];
      float o1 = S1/Z + b2[1];
      float mm = fmaxf(o0,o1);
      float lse = mm + logf(__expf(o0-mm)+__expf(o1-mm));
      acc0 += 0.25f*(o0 - lse);
      acc1 += 0.25f*(o1 - lse);
    }
  }
  if (t==0){ out[bb*2+0]=acc0; out[bb*2+1]=acc1; }
}

extern "C" void kernel_launch(void* const* d_in, const int* in_sizes, int n_in,
                              void* d_out, int out_size, void* d_ws, size_t ws_size,
                              hipStream_t stream) {
  const float* x      = (const float*)d_in[0];
  const float* emb    = (const float*)d_in[1];
  const int*   adj    = (const int*)d_in[2];
  const float* w1     = (const float*)d_in[3];
  const float* a_src1 = (const float*)d_in[4];
  const float* a_dst1 = (const float*)d_in[5];
  const float* b1     = (const float*)d_in[6];
  const float* w2     = (const float*)d_in[7];
  const float* a_src2 = (const float*)d_in[8];
  const float* a_dst2 = (const float*)d_in[9];
  const float* b2     = (const float*)d_in[10];

  float*    ws_h2   = (float*)d_ws;                       // 1 MB
  uint32_t* mask_ws = (uint32_t*)((char*)d_ws + WS_H2_BYTES);  // 256 KB

  mask_build<<<dim3(4096), dim3(256), 0, stream>>>(adj, mask_ws);
  gat_fused<<<dim3(1024), dim3(512), 0, stream>>>(x, emb, w1, a_src1, a_dst1,
                                                  b1, w2, mask_ws, ws_h2);
  gat_tail<<<dim3(128), dim3(256), 0, stream>>>(ws_h2, adj, a_src2, a_dst2, b2,
                                                (float*)d_out);
}